// Round 10
// baseline (26420.132 us; speedup 1.0000x reference)
//
#include <hip/hip_runtime.h>
#include <math.h>

#define Hh   512
#define TH   1536
#define LINN 128
typedef unsigned long long ull;
typedef unsigned int u32;

#define WS_A     0
#define WS_CC    6144
#define WS_RING0 16384
#define WS_RING1 49152
// ws usage ends at 81920 bytes

__device__ __forceinline__ float sigm(float v) { return 1.f / (1.f + __expf(-v)); }
__device__ __forceinline__ float tanh_fast(float x) { return 2.f / (1.f + __expf(-2.f * x)) - 1.f; }
__device__ __forceinline__ ull  pk(float v, u32 tag) { return ((ull)tag << 32) | (ull)__float_as_uint(v); }
__device__ __forceinline__ ull  ring_ld(const ull* p) {
    return __hip_atomic_load(p, __ATOMIC_RELAXED, __HIP_MEMORY_SCOPE_AGENT);
}
__device__ __forceinline__ void ring_st(ull* p, ull v) {
    __hip_atomic_store(p, v, __ATOMIC_RELAXED, __HIP_MEMORY_SCOPE_AGENT);
}

// Verify-only spin: assumes the initial load was already issued (batched with
// its siblings). Reloads ONLY this word; capped backoff from the 3rd reload.
#define SPIN_VERIFY(var, ptr, tag)                                    \
    {                                                                 \
        int _t = 0;                                                   \
        while ((u32)((var) >> 32) < (tag)) {                          \
            if (++_t > 2) __builtin_amdgcn_s_sleep(2);                \
            var = ring_ld(ptr);                                       \
        }                                                             \
    }

// ---------------------------------------------------------------- prep:
// A[row] = W_ih0[row,:]@W_proc ; CC[row] = W_ih0[row,:]@b_proc + b_ih0 (+ b_hh0 for r,z rows)
__global__ void prep(const float* __restrict__ Wih0, const float* __restrict__ Wproc,
                     const float* __restrict__ bproc, const float* __restrict__ bih0,
                     const float* __restrict__ bhh0, float* __restrict__ A,
                     float* __restrict__ CC)
{
    int row = blockIdx.x * 256 + threadIdx.x;
    if (row >= TH) return;
    const float* w = Wih0 + (size_t)row * LINN;
    float a = 0.f, c = 0.f;
    for (int k = 0; k < LINN; ++k) { float wv = w[k]; a = fmaf(wv, Wproc[k], a); c = fmaf(wv, bproc[k], c); }
    c += bih0[row];
    if (row < 2 * Hh) c += bhh0[row];
    A[row] = a; CC[row] = c;
}

// ---------------------------------------------------------------- ring init (tags + initial state, every call)
__global__ void ringinit(const float* __restrict__ mem, ull* __restrict__ ring0,
                         ull* __restrict__ ring1)
{
    const int t = threadIdx.x;          // 512 threads
    for (int slot = 0; slot < 8; ++slot) {
        ring0[slot * Hh + t] = pk(slot == 7 ? mem[t]      : 0.f, 0u);
        ring1[slot * Hh + t] = pk(slot == 7 ? mem[Hh + t] : 0.f, 0u);
    }
}

// ---------------------------------------------------------------- fused self-timed dataflow scan
// R8 structure verbatim; single delta: poll words are BATCH-ISSUED (all initial
// loads in flight before any verification) then per-word verified. Removes the
// chained-RTT serialization (L0: 2 chained -> 1, L1: 4 chained -> 1 common-case).
__launch_bounds__(256, 1)
__global__ void fused(const float* __restrict__ input, const float* __restrict__ resid,
                      const float* __restrict__ Whh0, const float* __restrict__ bhh0,
                      const float* __restrict__ A, const float* __restrict__ CC,
                      const float* __restrict__ Wih1, const float* __restrict__ Whh1,
                      const float* __restrict__ bih1, const float* __restrict__ bhh1,
                      ull* __restrict__ ring0, ull* __restrict__ ring1,
                      float* __restrict__ outp, int T)
{
    __shared__ __align__(16) float smem[13312];   // 52 KB: 24x512 weights + h buffers
    const int tid = threadIdx.x;
    const int wg  = blockIdx.x;

    if (wg < 64) {
        // ---------------- layer 0 ----------------
        float* Wl = smem;                  // [24][512]
        float* hl = smem + 12288;          // [512]
        const int jl = tid >> 5;           // 0..7   local h-index
        const int s2 = tid & 31;           // k-lane
        const int jg = wg * 8 + jl;
        for (int i = tid; i < 24 * Hh; i += 256) {
            int lr = i >> 9, k = i & (Hh - 1);
            int g = lr % 3, j = lr / 3;
            Wl[i] = Whh0[(size_t)(g * Hh + wg * 8 + j) * Hh + k];
        }
        const float Ar = A[jg], Az = A[jg + Hh], An = A[jg + 2 * Hh];
        const float Cr = CC[jg], Cz = CC[jg + Hh], Cn = CC[jg + 2 * Hh];
        const float Bn = bhh0[jg + 2 * Hh];
        const float4* W4 = (const float4*)Wl;    // row r -> float4 base r*128
        __syncthreads();

        for (int s = 0; s < T; ++s) {
            const float x = input[s];            // independent load, in flight early
            const ull* base = ring0 + (size_t)((s - 1) & 7) * Hh;
            const u32 tgt = (u32)s;
            // batch-issue: backpressure probe (tid0) + both data words, then verify
            ull bpw = 0;
            const ull* bp = ring1 + (size_t)((s - 7) & 7) * Hh;
            const bool dobp = (tid == 0) && (s >= 7);
            if (dobp) bpw = ring_ld(bp);
            ull w0 = ring_ld(base + tid);
            ull w1 = ring_ld(base + tid + 256);
            if (dobp) SPIN_VERIFY(bpw, bp, (u32)(s - 6));
            SPIN_VERIFY(w0, base + tid, tgt);
            SPIN_VERIFY(w1, base + tid + 256, tgt);
            __syncthreads();                     // all polls done -> safe to overwrite hl
            hl[tid]       = __uint_as_float((u32)w0);
            hl[tid + 256] = __uint_as_float((u32)w1);
            __syncthreads();
            const float4* hb4 = (const float4*)hl;
            float4 hv[4];
#pragma unroll
            for (int c = 0; c < 4; ++c) hv[c] = hb4[s2 + 32 * c];
            float acc[3];
#pragma unroll
            for (int g = 0; g < 3; ++g) {
                const float4* Wr = W4 + (jl * 3 + g) * 128;
                float a = 0.f;
#pragma unroll
                for (int c = 0; c < 4; ++c) {
                    const float4 w = Wr[s2 + 32 * c], h = hv[c];
                    a = fmaf(w.x, h.x, a); a = fmaf(w.y, h.y, a);
                    a = fmaf(w.z, h.z, a); a = fmaf(w.w, h.w, a);
                }
                acc[g] = a;
            }
#pragma unroll
            for (int o = 16; o > 0; o >>= 1) {
                acc[0] += __shfl_xor(acc[0], o);
                acc[1] += __shfl_xor(acc[1], o);
                acc[2] += __shfl_xor(acc[2], o);
            }
            if (s2 == 0) {
                const float r  = sigm(fmaf(Ar, x, Cr) + acc[0]);
                const float z  = sigm(fmaf(Az, x, Cz) + acc[1]);
                const float n  = tanh_fast(fmaf(An, x, Cn) + r * (acc[2] + Bn));
                const float hn = (1.f - z) * n + z * hl[jg];
                ring_st(ring0 + (size_t)(s & 7) * Hh + jg, pk(hn, (u32)(s + 1)));
                if (s == T - 1) outp[Hh + jg] = hn;
            }
        }
    } else {
        // ---------------- layer 1 (lag 1) ----------------
        float* Wl  = smem;                 // [24][512]: per h: ihR,ihZ,ihN,hhR,hhZ,hhN
        float* hl0 = smem + 12288;         // [512]
        float* hl1 = smem + 12800;         // [512]
        const int w  = tid >> 6;           // wave 0..3 -> h-subindex
        const int l  = tid & 63;
        const int jg = (wg - 64) * 4 + w;
        for (int i = tid; i < 24 * Hh; i += 256) {
            int lr = i >> 9, k = i & (Hh - 1);
            int ww = lr / 6, q = lr % 6;
            int hj = (wg - 64) * 4 + ww;
            const float* src = (q < 3) ? &Wih1[(size_t)(q * Hh + hj) * Hh]
                                       : &Whh1[(size_t)((q - 3) * Hh + hj) * Hh];
            Wl[i] = src[k];
        }
        const float Br  = bih1[jg] + bhh1[jg];
        const float Bz  = bih1[jg + Hh] + bhh1[jg + Hh];
        const float Bin = bih1[jg + 2 * Hh];
        const float Bhn = bhh1[jg + 2 * Hh];
        const float4* W4 = (const float4*)Wl;
        float resl = resid[jg];            // live in lane 0 of each wave
        __syncthreads();

        for (int u = 0; u < T; ++u) {
            const ull* b0 = ring0 + (size_t)(u & 7) * Hh;          // h0[u], tag u+1
            const ull* b1 = ring1 + (size_t)((u - 1) & 7) * Hh;    // h1[u-1], tag u
            const u32 t0g = (u32)(u + 1), t1g = (u32)u;
            // batch-issue all four, then verify each
            ull a0 = ring_ld(b0 + tid);
            ull a1 = ring_ld(b0 + tid + 256);
            ull c0 = ring_ld(b1 + tid);
            ull c1 = ring_ld(b1 + tid + 256);
            SPIN_VERIFY(c0, b1 + tid, t1g);
            SPIN_VERIFY(c1, b1 + tid + 256, t1g);
            SPIN_VERIFY(a0, b0 + tid, t0g);
            SPIN_VERIFY(a1, b0 + tid + 256, t0g);
            __syncthreads();                 // all polls done -> safe to overwrite hl0/hl1
            hl0[tid]       = __uint_as_float((u32)a0);
            hl0[tid + 256] = __uint_as_float((u32)a1);
            hl1[tid]       = __uint_as_float((u32)c0);
            hl1[tid + 256] = __uint_as_float((u32)c1);
            __syncthreads();
            const float4* h04 = (const float4*)hl0;
            const float4* h14 = (const float4*)hl1;
            float4 x0[2], x1[2];
#pragma unroll
            for (int c = 0; c < 2; ++c) { x0[c] = h04[l + 64 * c]; x1[c] = h14[l + 64 * c]; }
            float ai[3], ah[3];
#pragma unroll
            for (int g = 0; g < 3; ++g) {
                const float4* Wi = W4 + (w * 6 + g) * 128;
                const float4* Wh = W4 + (w * 6 + 3 + g) * 128;
                float s1 = 0.f, s2v = 0.f;
#pragma unroll
                for (int c = 0; c < 2; ++c) {
                    const float4 wi = Wi[l + 64 * c], wh = Wh[l + 64 * c];
                    s1  = fmaf(wi.x, x0[c].x, s1);  s1  = fmaf(wi.y, x0[c].y, s1);
                    s1  = fmaf(wi.z, x0[c].z, s1);  s1  = fmaf(wi.w, x0[c].w, s1);
                    s2v = fmaf(wh.x, x1[c].x, s2v); s2v = fmaf(wh.y, x1[c].y, s2v);
                    s2v = fmaf(wh.z, x1[c].z, s2v); s2v = fmaf(wh.w, x1[c].w, s2v);
                }
                ai[g] = s1; ah[g] = s2v;
            }
#pragma unroll
            for (int o = 32; o > 0; o >>= 1) {
                ai[0] += __shfl_xor(ai[0], o); ai[1] += __shfl_xor(ai[1], o); ai[2] += __shfl_xor(ai[2], o);
                ah[0] += __shfl_xor(ah[0], o); ah[1] += __shfl_xor(ah[1], o); ah[2] += __shfl_xor(ah[2], o);
            }
            if (l == 0) {
                const float r   = sigm(ai[0] + ah[0] + Br);
                const float z   = sigm(ai[1] + ah[1] + Bz);
                const float n   = tanh_fast(ai[2] + Bin + r * (ah[2] + Bhn));
                const float h1n = (1.f - z) * n + z * hl1[jg];
                ring_st(ring1 + (size_t)(u & 7) * Hh + jg, pk(h1n, (u32)(u + 1)));
                resl = sigm(resl + h1n);
                if (u == T - 1) { outp[jg] = resl; outp[2 * Hh + jg] = h1n; }
            }
        }
    }
}

// ---------------------------------------------------------------- host
extern "C" void kernel_launch(void* const* d_in, const int* in_sizes, int n_in,
                              void* d_out, int out_size, void* d_ws, size_t ws_size,
                              hipStream_t stream)
{
    const float* input    = (const float*)d_in[0];
    const float* residual = (const float*)d_in[1];
    const float* memory   = (const float*)d_in[2];
    const float* Wproc    = (const float*)d_in[3];
    const float* bproc    = (const float*)d_in[4];
    const float* Wih0     = (const float*)d_in[5];
    const float* Whh0     = (const float*)d_in[6];
    const float* bih0     = (const float*)d_in[7];
    const float* bhh0     = (const float*)d_in[8];
    const float* Wih1     = (const float*)d_in[9];
    const float* Whh1     = (const float*)d_in[10];
    const float* bih1     = (const float*)d_in[11];
    const float* bhh1     = (const float*)d_in[12];
    const int L = in_sizes[0];
    const int T = L - 1;
    float* out = (float*)d_out;
    char* ws = (char*)d_ws;

    float* A     = (float*)(ws + WS_A);
    float* CC    = (float*)(ws + WS_CC);
    ull*   ring0 = (ull*)(ws + WS_RING0);
    ull*   ring1 = (ull*)(ws + WS_RING1);

    prep<<<dim3((TH + 255) / 256), dim3(256), 0, stream>>>(Wih0, Wproc, bproc, bih0, bhh0, A, CC);
    ringinit<<<dim3(1), dim3(512), 0, stream>>>(memory, ring0, ring1);
    fused<<<dim3(192), dim3(256), 0, stream>>>(input, residual, Whh0, bhh0, A, CC,
                                               Wih1, Whh1, bih1, bhh1,
                                               ring0, ring1, out, T);
}